// Round 2
// baseline (377.459 us; speedup 1.0000x reference)
//
#include <hip/hip_runtime.h>
#include <math.h>

#define THREADS 256

// scale_l = 8 * 256^(l/15) - 1 ; res_l = ceil(scale_l)+1 (dense only for l<4)
static __device__ __constant__ float kScale[16] = {
    7.0f,          10.57815398f,  15.75670563f,  23.25146503f,
    34.09839735f,  49.79683366f,  72.51669472f,  105.39843246f,
    152.98718950f, 221.86092960f, 321.53978800f, 465.80191600f,
    674.58804640f, 976.75780270f, 1414.07882380f, 2047.0f};
static __device__ __constant__ int kRes[4] = {8, 12, 17, 25};

__global__ void __launch_bounds__(THREADS)
htrf_fused(const float* __restrict__ xyzs, const float* __restrict__ dirs,
           const float* __restrict__ grid, const float* __restrict__ W1,
           const float* __restrict__ W2, const float* __restrict__ Wc1,
           const float* __restrict__ Wc2, const float* __restrict__ Wc3,
           float* __restrict__ out, int N) {
  // per-thread private scratch; stride 33 => bank (t+k)%32, 2-way alias = free
  __shared__ float sbuf[THREADS * 33];
  const int tid = threadIdx.x;
  const int n = blockIdx.x * THREADS + tid;
  if (n >= N) return;
  float* __restrict__ my = sbuf + tid * 33;

  const float4 p = reinterpret_cast<const float4*>(xyzs)[n];
  const float q0 = (p.x + 1.0f) * 0.5f;
  const float q1 = (p.y + 1.0f) * 0.5f;
  const float q2 = (p.z + 1.0f) * 0.5f;
  const float q3 = p.w;

  // ---------------- hash-grid encode ----------------
  #pragma unroll 1
  for (int l = 0; l < 16; ++l) {
    const float s = kScale[l];
    const float pos0 = fmaf(q0, s, 0.5f);
    const float pos1 = fmaf(q1, s, 0.5f);
    const float pos2 = fmaf(q2, s, 0.5f);
    const float pos3 = fmaf(q3, s, 0.5f);
    const float fl0 = floorf(pos0), fl1 = floorf(pos1);
    const float fl2 = floorf(pos2), fl3 = floorf(pos3);
    const float f0 = pos0 - fl0, f1 = pos1 - fl1;
    const float f2 = pos2 - fl2, f3 = pos3 - fl3;
    const int g0 = (int)fl0, g1 = (int)fl1, g2 = (int)fl2, g3 = (int)fl3;

    float wxy[4], wzt[4];
    {
      const float u0 = 1.0f - f0, u1 = 1.0f - f1, u2 = 1.0f - f2, u3 = 1.0f - f3;
      wxy[0] = u0 * u1; wxy[1] = f0 * u1; wxy[2] = u0 * f1; wxy[3] = f0 * f1;
      wzt[0] = u2 * u3; wzt[1] = f2 * u3; wzt[2] = u2 * f3; wzt[3] = f2 * f3;
    }

    unsigned idx[16];
    if (l < 4) {  // dense: idx = min(c0 + c1*r + c2*r^2 + c3*r^3, T-1)
      const int r = kRes[l];
      const int r2 = r * r, r3 = r2 * r;
      const int x0 = g0, x1 = g0 + 1;
      const int y0 = g1 * r, y1 = (g1 + 1) * r;
      const int z0 = g2 * r2, z1 = (g2 + 1) * r2;
      const int t0 = g3 * r3, t1 = (g3 + 1) * r3;
      const int sxy[4] = {x0 + y0, x1 + y0, x0 + y1, x1 + y1};
      const int szt[4] = {z0 + t0, z1 + t0, z0 + t1, z1 + t1};
      #pragma unroll
      for (int cc = 0; cc < 16; ++cc) {
        const int v = sxy[cc & 3] + szt[cc >> 2];
        idx[cc] = (unsigned)(v < (1 << 19) - 1 ? v : (1 << 19) - 1);
      }
    } else {  // hashed: XOR of per-dim corner*prime
      const unsigned x0 = (unsigned)g0,               x1 = (unsigned)(g0 + 1);
      const unsigned y0 = (unsigned)g1 * 2654435761u, y1 = (unsigned)(g1 + 1) * 2654435761u;
      const unsigned z0 = (unsigned)g2 * 805459861u,  z1 = (unsigned)(g2 + 1) * 805459861u;
      const unsigned t0 = (unsigned)g3 * 3674351687u, t1 = (unsigned)(g3 + 1) * 3674351687u;
      const unsigned sxy[4] = {x0 ^ y0, x1 ^ y0, x0 ^ y1, x1 ^ y1};
      const unsigned szt[4] = {z0 ^ t0, z1 ^ t0, z0 ^ t1, z1 ^ t1};
      #pragma unroll
      for (int cc = 0; cc < 16; ++cc)
        idx[cc] = (sxy[cc & 3] ^ szt[cc >> 2]) & ((1u << 19) - 1u);
    }

    const float2* __restrict__ gl =
        reinterpret_cast<const float2*>(grid) + ((size_t)l << 19);
    float2 vv[16];
    #pragma unroll
    for (int cc = 0; cc < 16; ++cc) vv[cc] = gl[idx[cc]];  // 16 indep loads in flight
    float a0 = 0.0f, a1 = 0.0f;
    #pragma unroll
    for (int cc = 0; cc < 16; ++cc) {
      const float w = wxy[cc & 3] * wzt[cc >> 2];
      a0 = fmaf(w, vv[cc].x, a0);
      a1 = fmaf(w, vv[cc].y, a1);
    }
    my[2 * l]     = a0;  // dynamic LDS index OK (not a register array)
    my[2 * l + 1] = a1;
  }

  // ---------------- MLP1: 32 -> 64(relu) -> 16, fused accumulate ----------------
  float fr[32];
  #pragma unroll
  for (int k = 0; k < 32; ++k) fr[k] = my[k];

  float h[16];
  #pragma unroll
  for (int i = 0; i < 16; ++i) h[i] = 0.0f;

  #pragma unroll 1
  for (int j = 0; j < 64; ++j) {  // j uniform -> W rows via s_load, SGPR fmac operands
    const float* __restrict__ w = W1 + j * 32;
    float b0 = 0.f, b1 = 0.f, b2 = 0.f, b3 = 0.f;
    #pragma unroll
    for (int k = 0; k < 32; k += 4) {
      b0 = fmaf(fr[k + 0], w[k + 0], b0);
      b1 = fmaf(fr[k + 1], w[k + 1], b1);
      b2 = fmaf(fr[k + 2], w[k + 2], b2);
      b3 = fmaf(fr[k + 3], w[k + 3], b3);
    }
    const float act = fmaxf((b0 + b1) + (b2 + b3), 0.0f);
    #pragma unroll
    for (int i = 0; i < 16; ++i) h[i] = fmaf(act, W2[i * 64 + j], h[i]);
  }
  const float sigma = expf(h[0]);

  // ---------------- SH degree-4 + concat ----------------
  const float dxr = dirs[3 * n + 0], dyr = dirs[3 * n + 1], dzr = dirs[3 * n + 2];
  const float x = fmaf(dxr, 2.0f, -1.0f);
  const float y = fmaf(dyr, 2.0f, -1.0f);
  const float z = fmaf(dzr, 2.0f, -1.0f);
  const float xy = x * y, xz = x * z, yz = y * z;
  const float x2 = x * x, y2 = y * y, z2 = z * z;
  float ci[32];
  ci[0]  = 0.28209479177387814f;
  ci[1]  = -0.48860251190291987f * y;
  ci[2]  = 0.48860251190291987f * z;
  ci[3]  = -0.48860251190291987f * x;
  ci[4]  = 1.0925484305920792f * xy;
  ci[5]  = -1.0925484305920792f * yz;
  ci[6]  = 0.94617469575756f * z2 - 0.31539156525252f;
  ci[7]  = -1.0925484305920792f * xz;
  ci[8]  = 0.5462742152960396f * x2 - 0.5462742152960396f * y2;
  ci[9]  = 0.5900435899266435f * y * (-3.0f * x2 + y2);
  ci[10] = 2.890611442640554f * xy * z;
  ci[11] = 0.4570457994644657f * y * (1.0f - 5.0f * z2);
  ci[12] = 0.3731763325901154f * z * (5.0f * z2 - 3.0f);
  ci[13] = 0.4570457994644657f * x * (1.0f - 5.0f * z2);
  ci[14] = 1.445305721320277f * z * (x2 - y2);
  ci[15] = 0.5900435899266435f * x * (-x2 + 3.0f * y2);
  #pragma unroll
  for (int i = 0; i < 16; ++i) ci[16 + i] = h[i];

  // ---------------- color MLP: 32 -> 64(relu) -> 64(relu) -> 3(sigmoid) ----------------
  float c2p[64];
  #pragma unroll
  for (int i = 0; i < 64; ++i) c2p[i] = 0.0f;

  #pragma unroll 1
  for (int j = 0; j < 64; ++j) {
    const float* __restrict__ w = Wc1 + j * 32;
    float b0 = 0.f, b1 = 0.f, b2 = 0.f, b3 = 0.f;
    #pragma unroll
    for (int k = 0; k < 32; k += 4) {
      b0 = fmaf(ci[k + 0], w[k + 0], b0);
      b1 = fmaf(ci[k + 1], w[k + 1], b1);
      b2 = fmaf(ci[k + 2], w[k + 2], b2);
      b3 = fmaf(ci[k + 3], w[k + 3], b3);
    }
    const float act = fmaxf((b0 + b1) + (b2 + b3), 0.0f);
    #pragma unroll
    for (int i = 0; i < 64; ++i) c2p[i] = fmaf(act, Wc2[i * 64 + j], c2p[i]);
  }

  float l0a = 0.f, l0b = 0.f, l1a = 0.f, l1b = 0.f, l2a = 0.f, l2b = 0.f;
  #pragma unroll
  for (int i = 0; i < 64; i += 2) {
    const float a0r = fmaxf(c2p[i], 0.0f);
    const float a1r = fmaxf(c2p[i + 1], 0.0f);
    l0a = fmaf(a0r, Wc3[0 * 64 + i], l0a);
    l0b = fmaf(a1r, Wc3[0 * 64 + i + 1], l0b);
    l1a = fmaf(a0r, Wc3[1 * 64 + i], l1a);
    l1b = fmaf(a1r, Wc3[1 * 64 + i + 1], l1b);
    l2a = fmaf(a0r, Wc3[2 * 64 + i], l2a);
    l2b = fmaf(a1r, Wc3[2 * 64 + i + 1], l2b);
  }
  const float col0 = 1.0f / (1.0f + expf(-(l0a + l0b)));
  const float col1 = 1.0f / (1.0f + expf(-(l1a + l1b)));
  const float col2 = 1.0f / (1.0f + expf(-(l2a + l2b)));

  out[3 * n + 0] = col0;
  out[3 * n + 1] = col1;
  out[3 * n + 2] = col2;
  out[3 * N + n] = sigma;
}

extern "C" void kernel_launch(void* const* d_in, const int* in_sizes, int n_in,
                              void* d_out, int out_size, void* d_ws, size_t ws_size,
                              hipStream_t stream) {
  const int N = in_sizes[0] / 4;
  htrf_fused<<<dim3((N + THREADS - 1) / THREADS), dim3(THREADS), 0, stream>>>(
      (const float*)d_in[0], (const float*)d_in[1], (const float*)d_in[2],
      (const float*)d_in[3], (const float*)d_in[4], (const float*)d_in[5],
      (const float*)d_in[6], (const float*)d_in[7], (float*)d_out, N);
}